// Round 3
// baseline (77.598 us; speedup 1.0000x reference)
//
#include <hip/hip_runtime.h>
#include <math.h>

#define RR      300   // rois per image
#define NCLS    21    // classes incl background
#define NFG     20    // foreground classes
#define KK      21    // output pad size (== num_classes)
#define THREADS 640   // 10 waves
#define JJ      320   // padded j-slots (5 * 64)
#define NW32    10    // 32-bit keep words per row
#define NMS_THR 0.3f

// Block FMA contraction: t = a*b rounded separately, then + c. (bit-exact vs ref, proven R1/R2)
__device__ __forceinline__ float madd_nofma(float a, float b, float c) {
    float t = a * b;
    asm volatile("" : "+v"(t));
    return t + c;
}

// Correctly-rounded float32 exp via double (bit-exact vs ref, proven R1/R2)
__device__ __forceinline__ float exp_acc(float x) {
    return (float)exp((double)x);
}

__global__ __launch_bounds__(THREADS)
void nms_per_class_kernel(const float* __restrict__ cls_prob,   // [B,RR,NCLS]
                          const float* __restrict__ rois,       // [B,RR,5]
                          const float* __restrict__ bbox_pred,  // [B,RR,4*NCLS]
                          const float* __restrict__ im_info,    // [B,3]
                          const float* __restrict__ thr,        // [NCLS]
                          float* __restrict__ wsBoxes,          // [B,NFG,KK,4] compact kept boxes
                          int*   __restrict__ wsCount)          // [B,NFG] full kept count
{
    const int blk = blockIdx.x;
    const int b   = blk / NFG;
    const int ci  = blk % NFG;
    const int c   = ci + 1;          // skip background
    const int tid  = threadIdx.x;
    const int lane = tid & 63;
    const int wave = tid >> 6;

    __shared__ float  s_sm[JJ];          // masked scores (-inf if below threshold)
    __shared__ float4 s_sbox[JJ];        // boxes in score-rank order (padded)
    __shared__ float  s_area[JJ];
    __shared__ unsigned int s_sup[RR * NW32];  // suppression bits, row-major (40B rows, 8B aligned)
    __shared__ unsigned int s_keepw[NW32];
    __shared__ int s_nvalid;

    if (tid == 0) s_nvalid = 0;

    const float imH = im_info[b * 3 + 0];
    const float imW = im_info[b * 3 + 1];
    const float t   = thr[c];

    // ---- Phase A: masked scores + wave-ballot valid count + pad slots ----
    if (tid < RR) {
        float s = cls_prob[(b * RR + tid) * NCLS + c];
        bool valid = s > t;
        s_sm[tid] = valid ? s : -INFINITY;
        unsigned long long m = __ballot(valid);
        if (lane == 0) atomicAdd(&s_nvalid, __popcll(m));
    } else if (tid < JJ) {
        s_sm[tid]   = -INFINITY;
        s_sbox[tid] = make_float4(0.f, 0.f, 0.f, 0.f);
        s_area[tid] = 0.f;
    }
    __syncthreads();

    // ---- Phase B: stable rank (== argsort(-sm)) + decode into sorted slot ----
    if (tid < RR) {
        const float key = s_sm[tid];
        int rank = 0;
        #pragma unroll 10
        for (int j = 0; j < RR; ++j) {
            float kj = s_sm[j];
            rank += (kj > key || (kj == key && j < tid)) ? 1 : 0;
        }
        // decode roi for class c (expression forms identical to R1/R2 — bit-exact)
        float x1 = rois[(b * RR + tid) * 5 + 1];
        float y1 = rois[(b * RR + tid) * 5 + 2];
        float x2 = rois[(b * RR + tid) * 5 + 3];
        float y2 = rois[(b * RR + tid) * 5 + 4];
        float w  = x2 - x1 + 1.0f;
        float h  = y2 - y1 + 1.0f;
        float cx = x1 + 0.5f * w;
        float cy = y1 + 0.5f * h;
        const float* dp = &bbox_pred[((b * RR + tid) * NCLS + c) * 4];
        float dx = dp[0] * 0.1f;
        float dy = dp[1] * 0.1f;
        float dw = dp[2] * 0.2f;
        float dh = dp[3] * 0.2f;
        float pcx = madd_nofma(dx, w, cx);
        float pcy = madd_nofma(dy, h, cy);
        float pw  = exp_acc(dw) * w;
        float ph  = exp_acc(dh) * h;
        float bx1 = fminf(fmaxf(pcx - 0.5f * pw, 0.0f), imW - 1.0f);
        float by1 = fminf(fmaxf(pcy - 0.5f * ph, 0.0f), imH - 1.0f);
        float bx2 = fminf(fmaxf(pcx + 0.5f * pw, 0.0f), imW - 1.0f);
        float by2 = fminf(fmaxf(pcy + 0.5f * ph, 0.0f), imH - 1.0f);
        s_sbox[rank] = make_float4(bx1, by1, bx2, by2);
        s_area[rank] = (bx2 - bx1 + 1.0f) * (by2 - by1 + 1.0f);
    }
    __syncthreads();

    const int nv = s_nvalid;

    // ---- Phase C: suppression matrix via ballot over 15 upper-triangle 64x64 tiles ----
    // Tile t -> (q = j-block, ib = i-block), ib <= q, enumerated q-major.
    for (int t2 = wave; t2 < 15; t2 += 10) {
        int q = 0, base = 0;
        while (t2 >= base + (q + 1)) { base += q + 1; ++q; }
        const int ib = t2 - base;
        const int j  = (q << 6) + lane;
        const int iLim  = (nv < ((q + 1) << 6)) ? nv : ((q + 1) << 6);
        const int iBase = ib << 6;
        if (iBase < iLim) {
            const float4 bj = s_sbox[j];     // one ds_read_b128, coalesced
            const float  aj = s_area[j];
            #pragma unroll 2
            for (int i = iBase; i < iLim; ++i) {
                const float4 bi = s_sbox[i]; // broadcast read
                const float  ai = s_area[i];
                float xx1 = fmaxf(bi.x, bj.x);
                float yy1 = fmaxf(bi.y, bj.y);
                float xx2 = fminf(bi.z, bj.z);
                float yy2 = fminf(bi.w, bj.w);
                float inter = fmaxf(xx2 - xx1 + 1.0f, 0.0f) * fmaxf(yy2 - yy1 + 1.0f, 0.0f);
                float iou = inter / (ai + aj - inter);
                bool sup = (iou > NMS_THR) && (j > i) && (j < nv);
                unsigned long long m = __ballot(sup);
                if (lane == 0)
                    *(unsigned long long*)&s_sup[i * NW32 + 2 * q] = m;
            }
        }
    }
    __syncthreads();

    // ---- Phase D: serial greedy scan, one wave, 10 lanes own keep words ----
    if (tid < 64) {
        const int lw = (tid < NW32) ? tid : 0;
        const int lo = lw * 32;
        unsigned int rem = (nv >= lo + 32) ? 0xFFFFFFFFu
                         : (nv <= lo ? 0u : ((1u << (nv - lo)) - 1u));
        #pragma unroll 4
        for (int i = 0; i < nv; ++i) {
            unsigned int sv = (lo + 32 > i) ? s_sup[i * NW32 + lw] : 0u;
            unsigned int wsel = (unsigned int)__builtin_amdgcn_readlane((int)rem, i >> 5);
            unsigned int alive = (wsel >> (i & 31)) & 1u;
            rem &= ~(sv & (0u - alive));
        }
        if (tid < NW32) s_keepw[lw] = rem;
    }
    __syncthreads();

    // ---- Phase E: count + parallel compaction of first KK kept boxes ----
    if (tid == 0) {
        int total = 0;
        #pragma unroll
        for (int q = 0; q < NW32; ++q) total += __popc(s_keepw[q]);
        wsCount[b * NFG + ci] = total;
    }
    if (tid < RR) {
        const int w = tid >> 5, bit = tid & 31;
        const unsigned int kw = s_keepw[w];
        if ((kw >> bit) & 1u) {
            int pre = 0;
            for (int q = 0; q < w; ++q) pre += __popc(s_keepw[q]);
            pre += __popc(kw & ((1u << bit) - 1u));
            if (pre < KK) {
                float4 v = s_sbox[tid];
                float* dst = wsBoxes + (((size_t)(b * NFG + ci)) * KK + pre) * 4;
                dst[0] = v.x; dst[1] = v.y; dst[2] = v.z; dst[3] = v.w;
            }
        }
    }
}

__global__ __launch_bounds__(64)
void select_topk_kernel(const float* __restrict__ wsBoxes,
                        const int*   __restrict__ wsCount,
                        float* __restrict__ out,   // [B,KK,5] then [B] counts
                        int B)
{
    const int b = blockIdx.x;
    const int tid = threadIdx.x;

    __shared__ int s_pref[NFG + 1];
    __shared__ int s_n;

    if (tid == 0) {
        int acc = 0, full = 0;
        for (int q = 0; q < NFG; ++q) {
            s_pref[q] = acc;
            int cc = wsCount[b * NFG + q];
            acc += (cc < KK) ? cc : KK;
            full += cc;
        }
        s_pref[NFG] = acc;
        s_n = (full < KK) ? full : KK;
    }
    __syncthreads();

    const int n = s_n;
    if (tid < KK) {
        float* ob = out + (size_t)b * (KK * 5) + tid * 5;
        if (tid < n) {
            int cc = 0;
            for (int q = 1; q < NFG; ++q) if (s_pref[q] <= tid) cc = q;
            const int slot = tid - s_pref[cc];
            const float* bp = wsBoxes + (((size_t)(b * NFG + cc)) * KK + slot) * 4;
            ob[0] = bp[0];
            ob[1] = bp[1];
            ob[2] = bp[2];
            ob[3] = bp[3];
            ob[4] = (float)(cc + 1);
        } else {
            ob[0] = 0.0f; ob[1] = 0.0f; ob[2] = 0.0f; ob[3] = 0.0f; ob[4] = 0.0f;
        }
    }
    if (tid == 0) out[(size_t)B * KK * 5 + b] = (float)n;
}

extern "C" void kernel_launch(void* const* d_in, const int* in_sizes, int n_in,
                              void* d_out, int out_size, void* d_ws, size_t ws_size,
                              hipStream_t stream)
{
    const float* cls_prob  = (const float*)d_in[0];
    const float* rois      = (const float*)d_in[1];
    const float* bbox_pred = (const float*)d_in[2];
    const float* im_info   = (const float*)d_in[3];
    const float* thr       = (const float*)d_in[4];
    const int B = in_sizes[3] / 3;   // im_info is [B,3]

    float* wsBoxes = (float*)d_ws;                                         // B*NFG*KK*4 floats
    int*   wsCount = (int*)((char*)d_ws + (size_t)B * NFG * KK * 4 * sizeof(float));

    nms_per_class_kernel<<<B * NFG, THREADS, 0, stream>>>(
        cls_prob, rois, bbox_pred, im_info, thr, wsBoxes, wsCount);
    select_topk_kernel<<<B, 64, 0, stream>>>(
        wsBoxes, wsCount, (float*)d_out, B);
}

// Round 4
// 58.740 us; speedup vs baseline: 1.3210x; 1.3210x over previous
//
#include <hip/hip_runtime.h>
#include <math.h>

#define RR      300   // rois per image
#define NCLS    21    // classes incl background
#define NFG     20    // foreground classes
#define KK      21    // output pad size (== num_classes)
#define NMS_THR 0.3f

// Block FMA contraction: t = a*b rounded separately, then + c. (bit-exact vs ref, proven R1-R3)
__device__ __forceinline__ float madd_nofma(float a, float b, float c) {
    float t = a * b;
    asm volatile("" : "+v"(t));
    return t + c;
}

// Correctly-rounded float32 exp via double (bit-exact vs ref, proven R1-R3)
__device__ __forceinline__ float exp_acc(float x) {
    return (float)exp((double)x);
}

__device__ __forceinline__ float rdlane_f(float v, int l) {
    return __int_as_float(__builtin_amdgcn_readlane(__float_as_int(v), l));
}

// One wave per (image, fg-class). No __syncthreads anywhere.
__global__ __launch_bounds__(64)
void nms_per_class_kernel(const float* __restrict__ cls_prob,   // [B,RR,NCLS]
                          const float* __restrict__ rois,       // [B,RR,5]
                          const float* __restrict__ bbox_pred,  // [B,RR,4*NCLS]
                          const float* __restrict__ im_info,    // [B,3]
                          const float* __restrict__ thr,        // [NCLS]
                          float* __restrict__ wsBoxes,          // [B,NFG,KK,4] compact kept boxes
                          int*   __restrict__ wsCount)          // [B,NFG] full kept count
{
    const int blk  = blockIdx.x;
    const int b    = blk / NFG;
    const int ci   = blk % NFG;
    const int c    = ci + 1;          // skip background
    const int lane = threadIdx.x;     // 0..63

    __shared__ __align__(16) float s_scores[RR + 4]; // compacted valid scores (+pad)
    __shared__ int s_orig[RR];                       // compacted original roi index
    __shared__ int s_sorted[RR];                     // orig roi index in score-rank order

    const float imH = im_info[b * 3 + 0];
    const float imW = im_info[b * 3 + 1];
    const float t   = thr[c];

    // ---- Phase 1: load my 5 slot scores; ballot-compact valid ones ----
    int base = 0;
    #pragma unroll
    for (int s = 0; s < 5; ++s) {
        const int r  = s * 64 + lane;
        const bool in = (r < RR);
        const int rc = in ? r : 0;
        const float sc = cls_prob[(b * RR + rc) * NCLS + c];
        const bool valid = in && (sc > t);
        const unsigned long long m = __ballot(valid);
        if (valid) {
            const int pos = base + (int)__popcll(m & ((1ull << lane) - 1ull));
            s_scores[pos] = sc;
            s_orig[pos]   = r;
        }
        base += (int)__popcll(m);
    }
    const int nv = base;                       // uniform across wave
    if (lane < 4) s_scores[nv + lane] = -1.0f; // pad < any valid score (> 0.3)

    // ---- Phase 2: balanced stable rank over compacted scores ----
    // rank(k) = #{ j : s[j] > s[k]  or (s[j] == s[k] and j < k) }  (== stable argsort(-s))
    const int nv4 = (nv + 3) >> 2;
    for (int k = lane; k < nv; k += 64) {
        const float key = s_scores[k];
        int rank = 0;
        for (int q = 0; q < nv4; ++q) {
            const float4 v = *(const float4*)&s_scores[q * 4]; // broadcast (uniform addr)
            const int j0 = q * 4;
            rank += (v.x > key || (v.x == key && j0 + 0 < k)) ? 1 : 0;
            rank += (v.y > key || (v.y == key && j0 + 1 < k)) ? 1 : 0;
            rank += (v.z > key || (v.z == key && j0 + 2 < k)) ? 1 : 0;
            rank += (v.w > key || (v.w == key && j0 + 3 < k)) ? 1 : 0;
        }
        s_sorted[rank] = s_orig[k];
    }

    // ---- Phase 3: decode (verbatim expressions) directly into sorted-order regs ----
    float4 bx[5];
    float  area[5];
    unsigned keep = 0;
    #pragma unroll
    for (int s = 0; s < 5; ++s) {
        bx[s] = make_float4(0.f, 0.f, 0.f, 0.f);
        area[s] = 0.f;
        if (s * 64 < nv) {                          // uniform gate
            const int j  = s * 64 + lane;
            const bool in = (j < nv);
            const int r  = in ? s_sorted[j] : 0;
            float x1 = rois[(b * RR + r) * 5 + 1];
            float y1 = rois[(b * RR + r) * 5 + 2];
            float x2 = rois[(b * RR + r) * 5 + 3];
            float y2 = rois[(b * RR + r) * 5 + 4];
            float w  = x2 - x1 + 1.0f;
            float h  = y2 - y1 + 1.0f;
            float cx = x1 + 0.5f * w;
            float cy = y1 + 0.5f * h;
            const float* dp = &bbox_pred[((b * RR + r) * NCLS + c) * 4];
            float dx = dp[0] * 0.1f;
            float dy = dp[1] * 0.1f;
            float dw = dp[2] * 0.2f;
            float dh = dp[3] * 0.2f;
            float pcx = madd_nofma(dx, w, cx);
            float pcy = madd_nofma(dy, h, cy);
            float pw  = exp_acc(dw) * w;
            float ph  = exp_acc(dh) * h;
            float bx1 = fminf(fmaxf(pcx - 0.5f * pw, 0.0f), imW - 1.0f);
            float by1 = fminf(fmaxf(pcy - 0.5f * ph, 0.0f), imH - 1.0f);
            float bx2 = fminf(fmaxf(pcx + 0.5f * pw, 0.0f), imW - 1.0f);
            float by2 = fminf(fmaxf(pcy + 0.5f * ph, 0.0f), imH - 1.0f);
            bx[s]   = make_float4(bx1, by1, bx2, by2);
            area[s] = (bx2 - bx1 + 1.0f) * (by2 - by1 + 1.0f);
            keep |= (in ? 1u : 0u) << s;
        }
    }

    // ---- Phase 4: greedy scan; ctz skips suppressed boxes (bits cleared are permanent,
    //      so next-set-bit of the CURRENT mask is exactly the next alive candidate) ----
    #pragma unroll
    for (int w = 0; w < 5; ++w) {
        if (w * 64 < nv) {
            unsigned long long mask = __ballot((keep >> w) & 1u);
            while (mask) {
                const int tb = (int)__builtin_ctzll(mask);
                // broadcast box i = w*64+tb from owner lane's registers
                const float bix  = rdlane_f(bx[w].x, tb);
                const float biy  = rdlane_f(bx[w].y, tb);
                const float biz  = rdlane_f(bx[w].z, tb);
                const float biw  = rdlane_f(bx[w].w, tb);
                const float ar_i = rdlane_f(area[w], tb);
                #pragma unroll
                for (int s2 = w; s2 < 5; ++s2) {
                    if (s2 * 64 < nv) {             // uniform gate
                        float xx1 = fmaxf(bix, bx[s2].x);
                        float yy1 = fmaxf(biy, bx[s2].y);
                        float xx2 = fminf(biz, bx[s2].z);
                        float yy2 = fminf(biw, bx[s2].w);
                        float inter = fmaxf(xx2 - xx1 + 1.0f, 0.0f) * fmaxf(yy2 - yy1 + 1.0f, 0.0f);
                        float iou = inter / (ar_i + area[s2] - inter);
                        bool gtr = (s2 > w) || (lane > tb);     // j > i
                        bool sup = gtr && (iou > NMS_THR);
                        keep &= ~(((unsigned)sup) << s2);       // j >= nv bits already 0
                    }
                }
                mask = __ballot((keep >> w) & 1u) & ~((2ull << tb) - 1ull);
            }
        }
    }

    // ---- Phase 5: ballot prefix-popcount output compaction ----
    int total = 0;
    #pragma unroll
    for (int s = 0; s < 5; ++s) {
        const unsigned long long m = __ballot((keep >> s) & 1u);
        const bool mine = (keep >> s) & 1u;
        const int p = total + (int)__popcll(m & ((1ull << lane) - 1ull));
        if (mine && p < KK) {
            float* dst = wsBoxes + (((size_t)(b * NFG + ci)) * KK + p) * 4;
            *(float4*)dst = bx[s];
        }
        total += (int)__popcll(m);
    }
    if (lane == 0) wsCount[b * NFG + ci] = total;
}

__global__ __launch_bounds__(64)
void select_topk_kernel(const float* __restrict__ wsBoxes,
                        const int*   __restrict__ wsCount,
                        float* __restrict__ out,   // [B,KK,5] then [B] counts
                        int B)
{
    const int b = blockIdx.x;
    const int tid = threadIdx.x;

    __shared__ int s_pref[NFG + 1];
    __shared__ int s_n;

    if (tid == 0) {
        int acc = 0, full = 0;
        for (int q = 0; q < NFG; ++q) {
            s_pref[q] = acc;
            int cc = wsCount[b * NFG + q];
            acc += (cc < KK) ? cc : KK;
            full += cc;
        }
        s_pref[NFG] = acc;
        s_n = (full < KK) ? full : KK;
    }
    __syncthreads();

    const int n = s_n;
    if (tid < KK) {
        float* ob = out + (size_t)b * (KK * 5) + tid * 5;
        if (tid < n) {
            int cc = 0;
            for (int q = 1; q < NFG; ++q) if (s_pref[q] <= tid) cc = q;
            const int slot = tid - s_pref[cc];
            const float* bp = wsBoxes + (((size_t)(b * NFG + cc)) * KK + slot) * 4;
            ob[0] = bp[0];
            ob[1] = bp[1];
            ob[2] = bp[2];
            ob[3] = bp[3];
            ob[4] = (float)(cc + 1);
        } else {
            ob[0] = 0.0f; ob[1] = 0.0f; ob[2] = 0.0f; ob[3] = 0.0f; ob[4] = 0.0f;
        }
    }
    if (tid == 0) out[(size_t)B * KK * 5 + b] = (float)n;
}

extern "C" void kernel_launch(void* const* d_in, const int* in_sizes, int n_in,
                              void* d_out, int out_size, void* d_ws, size_t ws_size,
                              hipStream_t stream)
{
    const float* cls_prob  = (const float*)d_in[0];
    const float* rois      = (const float*)d_in[1];
    const float* bbox_pred = (const float*)d_in[2];
    const float* im_info   = (const float*)d_in[3];
    const float* thr       = (const float*)d_in[4];
    const int B = in_sizes[3] / 3;   // im_info is [B,3]

    float* wsBoxes = (float*)d_ws;                                         // B*NFG*KK*4 floats
    int*   wsCount = (int*)((char*)d_ws + (size_t)B * NFG * KK * 4 * sizeof(float));

    nms_per_class_kernel<<<B * NFG, 64, 0, stream>>>(
        cls_prob, rois, bbox_pred, im_info, thr, wsBoxes, wsCount);
    select_topk_kernel<<<B, 64, 0, stream>>>(
        wsBoxes, wsCount, (float*)d_out, B);
}

// Round 5
// 51.659 us; speedup vs baseline: 1.5021x; 1.1371x over previous
//
#include <hip/hip_runtime.h>
#include <math.h>

#define RR      300   // rois per image
#define NCLS    21    // classes incl background
#define NFG     20    // foreground classes
#define KK      21    // output pad size (== num_classes)
#define NMS_THR 0.3f

// Block FMA contraction: t = a*b rounded separately, then + c. (bit-exact vs ref, proven R1-R4)
__device__ __forceinline__ float madd_nofma(float a, float b, float c) {
    float t = a * b;
    asm volatile("" : "+v"(t));
    return t + c;
}

// Correctly-rounded float32 exp via double (bit-exact vs ref, proven R1-R4)
__device__ __forceinline__ float exp_acc(float x) {
    return (float)exp((double)x);
}

__device__ __forceinline__ float rdlane_f(float v, int l) {
    return __int_as_float(__builtin_amdgcn_readlane(__float_as_int(v), l));
}

// One wave per (image, fg-class). No __syncthreads anywhere.
__global__ __launch_bounds__(64)
void nms_per_class_kernel(const float* __restrict__ cls_prob,   // [B,RR,NCLS]
                          const float* __restrict__ rois,       // [B,RR,5]
                          const float* __restrict__ bbox_pred,  // [B,RR,4*NCLS]
                          const float* __restrict__ im_info,    // [B,3]
                          const float* __restrict__ thr,        // [NCLS]
                          float* __restrict__ wsBoxes,          // [B,NFG,KK,4] compact kept boxes
                          int*   __restrict__ wsCount)          // [B,NFG] full kept count
{
    const int blk  = blockIdx.x;
    const int b    = blk / NFG;
    const int ci   = blk % NFG;
    const int c    = ci + 1;          // skip background
    const int lane = threadIdx.x;     // 0..63

    __shared__ float4 s_box[RR];      // decoded boxes, ORIGINAL roi order
    __shared__ float  s_area[RR];
    __shared__ int    s_sorted[RR];   // original roi index at each sorted rank

    const float imH = im_info[b * 3 + 0];
    const float imW = im_info[b * 3 + 1];
    const float t   = thr[c];

    // ---- Phase 1: issue ALL global loads up front (one HBM latency total) ----
    float scp[5], rx1[5], ry1[5], rx2[5], ry2[5], d0[5], d1[5], d2[5], d3[5];
    #pragma unroll
    for (int s = 0; s < 5; ++s) {
        const int r  = s * 64 + lane;
        const int rc = (r < RR) ? r : 0;
        scp[s] = cls_prob[(b * RR + rc) * NCLS + c];
        const float* rp = &rois[(size_t)(b * RR + rc) * 5];
        rx1[s] = rp[1]; ry1[s] = rp[2]; rx2[s] = rp[3]; ry2[s] = rp[4];
        const float* dp = &bbox_pred[((size_t)(b * RR + rc) * NCLS + c) * 4];
        d0[s] = dp[0]; d1[s] = dp[1]; d2[s] = dp[2]; d3[s] = dp[3];
    }

    // ---- Phase 2: masked scores + valid count (register/ballot only) ----
    float msc[5];
    int nv = 0;
    #pragma unroll
    for (int s = 0; s < 5; ++s) {
        const int r = s * 64 + lane;
        const bool valid = (r < RR) && (scp[s] > t);
        msc[s] = valid ? scp[s] : -INFINITY;
        nv += (int)__popcll(__ballot(valid));
    }

    // ---- Phase 3: decode all boxes (verbatim expressions), park in LDS by orig index ----
    #pragma unroll
    for (int s = 0; s < 5; ++s) {
        const int r = s * 64 + lane;
        float x1 = rx1[s], y1 = ry1[s], x2 = rx2[s], y2 = ry2[s];
        float w  = x2 - x1 + 1.0f;
        float h  = y2 - y1 + 1.0f;
        float cx = x1 + 0.5f * w;
        float cy = y1 + 0.5f * h;
        float dx = d0[s] * 0.1f;
        float dy = d1[s] * 0.1f;
        float dw = d2[s] * 0.2f;
        float dh = d3[s] * 0.2f;
        float pcx = madd_nofma(dx, w, cx);
        float pcy = madd_nofma(dy, h, cy);
        float pw  = exp_acc(dw) * w;
        float ph  = exp_acc(dh) * h;
        float bx1 = fminf(fmaxf(pcx - 0.5f * pw, 0.0f), imW - 1.0f);
        float by1 = fminf(fmaxf(pcy - 0.5f * ph, 0.0f), imH - 1.0f);
        float bx2 = fminf(fmaxf(pcx + 0.5f * pw, 0.0f), imW - 1.0f);
        float by2 = fminf(fmaxf(pcy + 0.5f * ph, 0.0f), imH - 1.0f);
        if (r < RR) {
            s_box[r]  = make_float4(bx1, by1, bx2, by2);
            s_area[r] = (bx2 - bx1 + 1.0f) * (by2 - by1 + 1.0f);
        }
    }

    // ---- Phase 4: stable rank via v_readlane register broadcast (zero memory) ----
    // rank(k) = #{ j : s[j] > s[k]  or (s[j] == s[k] and j < k) }; phantoms (-inf,
    // idx>=300) provably rank >= 300 and are not written.
    int rank[5];
    #pragma unroll
    for (int s = 0; s < 5; ++s) rank[s] = 0;
    #pragma unroll
    for (int sj = 0; sj < 5; ++sj) {
        #pragma unroll 4
        for (int jj = 0; jj < 64; ++jj) {
            const float kj = rdlane_f(msc[sj], jj);
            #pragma unroll
            for (int s = 0; s < 5; ++s) {
                bool cnt;
                if (sj < s)       cnt = (kj >= msc[s]);                 // tie -> j<k
                else if (sj > s)  cnt = (kj >  msc[s]);                 // tie -> j>k
                else              cnt = (kj > msc[s]) || ((kj == msc[s]) && (jj < lane));
                rank[s] += cnt ? 1 : 0;
            }
        }
    }
    #pragma unroll
    for (int s = 0; s < 5; ++s) {
        const int k = s * 64 + lane;
        if (k < RR) s_sorted[rank[s]] = k;
    }

    // ---- Phase 5: gather decoded boxes into sorted-order registers ----
    float4 bx[5];
    float  area[5];
    unsigned keep = 0;
    #pragma unroll
    for (int s = 0; s < 5; ++s) {
        const int j   = s * 64 + lane;
        const int idx = (j < RR) ? s_sorted[j] : 0;
        bx[s]   = s_box[idx];
        area[s] = s_area[idx];
        keep |= ((j < nv) ? 1u : 0u) << s;
    }

    // ---- Phase 6: greedy scan; ctz skips suppressed boxes (proven R4) ----
    #pragma unroll
    for (int w = 0; w < 5; ++w) {
        if (w * 64 < nv) {
            unsigned long long mask = __ballot((keep >> w) & 1u);
            while (mask) {
                const int tb = (int)__builtin_ctzll(mask);
                const float bix  = rdlane_f(bx[w].x, tb);
                const float biy  = rdlane_f(bx[w].y, tb);
                const float biz  = rdlane_f(bx[w].z, tb);
                const float biw  = rdlane_f(bx[w].w, tb);
                const float ar_i = rdlane_f(area[w], tb);
                #pragma unroll
                for (int s2 = w; s2 < 5; ++s2) {
                    if (s2 * 64 < nv) {             // uniform gate
                        float xx1 = fmaxf(bix, bx[s2].x);
                        float yy1 = fmaxf(biy, bx[s2].y);
                        float xx2 = fminf(biz, bx[s2].z);
                        float yy2 = fminf(biw, bx[s2].w);
                        float inter = fmaxf(xx2 - xx1 + 1.0f, 0.0f) * fmaxf(yy2 - yy1 + 1.0f, 0.0f);
                        float iou = inter / (ar_i + area[s2] - inter);
                        bool gtr = (s2 > w) || (lane > tb);     // j > i
                        bool sup = gtr && (iou > NMS_THR);
                        keep &= ~(((unsigned)sup) << s2);       // j >= nv bits already 0
                    }
                }
                mask = __ballot((keep >> w) & 1u) & ~((2ull << tb) - 1ull);
            }
        }
    }

    // ---- Phase 7: ballot prefix-popcount output compaction ----
    int total = 0;
    #pragma unroll
    for (int s = 0; s < 5; ++s) {
        const unsigned long long m = __ballot((keep >> s) & 1u);
        const bool mine = (keep >> s) & 1u;
        const int p = total + (int)__popcll(m & ((1ull << lane) - 1ull));
        if (mine && p < KK) {
            float* dst = wsBoxes + (((size_t)(b * NFG + ci)) * KK + p) * 4;
            *(float4*)dst = bx[s];
        }
        total += (int)__popcll(m);
    }
    if (lane == 0) wsCount[b * NFG + ci] = total;
}

__global__ __launch_bounds__(64)
void select_topk_kernel(const float* __restrict__ wsBoxes,
                        const int*   __restrict__ wsCount,
                        float* __restrict__ out,   // [B,KK,5] then [B] counts
                        int B)
{
    const int b = blockIdx.x;
    const int tid = threadIdx.x;

    __shared__ int s_pref[NFG + 1];
    __shared__ int s_n;

    if (tid == 0) {
        int acc = 0, full = 0;
        for (int q = 0; q < NFG; ++q) {
            s_pref[q] = acc;
            int cc = wsCount[b * NFG + q];
            acc += (cc < KK) ? cc : KK;
            full += cc;
        }
        s_pref[NFG] = acc;
        s_n = (full < KK) ? full : KK;
    }
    __syncthreads();

    const int n = s_n;
    if (tid < KK) {
        float* ob = out + (size_t)b * (KK * 5) + tid * 5;
        if (tid < n) {
            int cc = 0;
            for (int q = 1; q < NFG; ++q) if (s_pref[q] <= tid) cc = q;
            const int slot = tid - s_pref[cc];
            const float* bp = wsBoxes + (((size_t)(b * NFG + cc)) * KK + slot) * 4;
            ob[0] = bp[0];
            ob[1] = bp[1];
            ob[2] = bp[2];
            ob[3] = bp[3];
            ob[4] = (float)(cc + 1);
        } else {
            ob[0] = 0.0f; ob[1] = 0.0f; ob[2] = 0.0f; ob[3] = 0.0f; ob[4] = 0.0f;
        }
    }
    if (tid == 0) out[(size_t)B * KK * 5 + b] = (float)n;
}

extern "C" void kernel_launch(void* const* d_in, const int* in_sizes, int n_in,
                              void* d_out, int out_size, void* d_ws, size_t ws_size,
                              hipStream_t stream)
{
    const float* cls_prob  = (const float*)d_in[0];
    const float* rois      = (const float*)d_in[1];
    const float* bbox_pred = (const float*)d_in[2];
    const float* im_info   = (const float*)d_in[3];
    const float* thr       = (const float*)d_in[4];
    const int B = in_sizes[3] / 3;   // im_info is [B,3]

    float* wsBoxes = (float*)d_ws;                                         // B*NFG*KK*4 floats
    int*   wsCount = (int*)((char*)d_ws + (size_t)B * NFG * KK * 4 * sizeof(float));

    nms_per_class_kernel<<<B * NFG, 64, 0, stream>>>(
        cls_prob, rois, bbox_pred, im_info, thr, wsBoxes, wsCount);
    select_topk_kernel<<<B, 64, 0, stream>>>(
        wsBoxes, wsCount, (float*)d_out, B);
}

// Round 7
// 45.287 us; speedup vs baseline: 1.7135x; 1.1407x over previous
//
#include <hip/hip_runtime.h>
#include <math.h>

#define RR      300   // rois per image
#define NCLS    21    // classes incl background
#define NFG     20    // foreground classes
#define KK      21    // output pad size (== num_classes)
#define NMS_THR 0.3f
#define THREADS 320   // 5 waves
#define PERW    60    // rois decoded/ranked per wave

// Block FMA contraction: t = a*b rounded separately, then + c. (bit-exact vs ref, proven R1-R5)
__device__ __forceinline__ float madd_nofma(float a, float b, float c) {
    float t = a * b;
    asm volatile("" : "+v"(t));
    return t + c;
}

// Correctly-rounded float32 exp via double (bit-exact vs ref, proven R1-R5)
__device__ __forceinline__ float exp_acc(float x) {
    return (float)exp((double)x);
}

__device__ __forceinline__ float rdlane_f(float v, int l) {
    return __int_as_float(__builtin_amdgcn_readlane(__float_as_int(v), l));
}

__device__ __forceinline__ unsigned long long rdlane_u64(unsigned long long v, int l) {
    unsigned lo = (unsigned)__builtin_amdgcn_readlane((int)(unsigned)(v & 0xFFFFFFFFull), l);
    unsigned hi = (unsigned)__builtin_amdgcn_readlane((int)(unsigned)(v >> 32), l);
    return ((unsigned long long)hi << 32) | lo;
}

// One block (5 waves) per (image, fg-class). Two-kernel structure (proven R1-R5);
// no cross-block communication.
__global__ __launch_bounds__(THREADS)
void nms_per_class_kernel(const float* __restrict__ cls_prob,   // [B,RR,NCLS]
                          const float* __restrict__ rois,       // [B,RR,5]
                          const float* __restrict__ bbox_pred,  // [B,RR,4*NCLS]
                          const float* __restrict__ im_info,    // [B,3]
                          const float* __restrict__ thr,        // [NCLS]
                          float* __restrict__ wsBoxes,          // [B,NFG,KK,4]
                          int*   __restrict__ wsCount)          // [B,NFG]
{
    const int blk  = blockIdx.x;
    const int b    = blk / NFG;
    const int ci   = blk % NFG;
    const int c    = ci + 1;                 // skip background
    const int lane = threadIdx.x & 63;
    const int wave = threadIdx.x >> 6;

    __shared__ float4 s_box[RR];             // decoded boxes, ORIGINAL roi order
    __shared__ int    s_sorted[RR];          // original roi index at each sorted rank

    const float imH = im_info[b * 3 + 0];
    const float imW = im_info[b * 3 + 1];
    const float t   = thr[c];

    // ---- own roi k = wave*60 + lane (lane<60): issue decode loads first ----
    const int  k   = wave * PERW + lane;
    const bool own = (lane < PERW);          // k < 300 guaranteed when own
    const int  kc  = own ? k : 0;
    const float* rp = &rois[(size_t)(b * RR + kc) * 5];
    const float x1 = rp[1], y1 = rp[2], x2 = rp[3], y2 = rp[4];
    const float* dp = &bbox_pred[((size_t)(b * RR + kc) * NCLS + c) * 4];
    const float e0 = dp[0], e1 = dp[1], e2 = dp[2], e3 = dp[3];
    const float sck = cls_prob[(b * RR + kc) * NCLS + c];

    // ---- j-side: all 300 scores as sortable u64 keys (each wave holds a copy) ----
    // key = (sortable_u32(score) << 32) | ~idx ; invalid -> hi=0. Unsigned compare
    // reproduces (score desc, idx asc) exactly: equal scores -> ~j > ~k  <=>  j < k.
    unsigned long long jkey[5];
    int nv = 0;
    #pragma unroll
    for (int s = 0; s < 5; ++s) {
        const int r  = s * 64 + lane;
        const int rc = (r < RR) ? r : 0;
        const float sc = cls_prob[(b * RR + rc) * NCLS + c];
        const bool valid = (r < RR) && (sc > t);
        const unsigned u = valid ? (__float_as_uint(sc) | 0x80000000u) : 0u;
        jkey[s] = ((unsigned long long)u << 32) | (unsigned)(~r);
        nv += (int)__popcll(__ballot(valid));
    }

    // ---- decode own box (verbatim expressions, proven bit-exact R1-R5) ----
    {
        float w  = x2 - x1 + 1.0f;
        float h  = y2 - y1 + 1.0f;
        float cx = x1 + 0.5f * w;
        float cy = y1 + 0.5f * h;
        float dx = e0 * 0.1f;
        float dy = e1 * 0.1f;
        float dw = e2 * 0.2f;
        float dh = e3 * 0.2f;
        float pcx = madd_nofma(dx, w, cx);
        float pcy = madd_nofma(dy, h, cy);
        float pw  = exp_acc(dw) * w;
        float ph  = exp_acc(dh) * h;
        float bx1 = fminf(fmaxf(pcx - 0.5f * pw, 0.0f), imW - 1.0f);
        float by1 = fminf(fmaxf(pcy - 0.5f * ph, 0.0f), imH - 1.0f);
        float bx2 = fminf(fmaxf(pcx + 0.5f * pw, 0.0f), imW - 1.0f);
        float by2 = fminf(fmaxf(pcy + 0.5f * ph, 0.0f), imH - 1.0f);
        if (own) s_box[k] = make_float4(bx1, by1, bx2, by2);
    }

    // ---- rank own roi k against all 300 via u64 readlane broadcast (zero memory) ----
    const bool vk = own && (sck > t);
    const unsigned uk = vk ? (__float_as_uint(sck) | 0x80000000u) : 0u;
    const unsigned long long mykey = ((unsigned long long)uk << 32) | (unsigned)(~k);
    int rank = 0;
    #pragma unroll
    for (int s = 0; s < 5; ++s) {
        const int lim = (s == 4) ? (RR - 256) : 64;   // skip phantom j >= 300
        const unsigned long long kv = jkey[s];
        #pragma unroll 4
        for (int jj = 0; jj < lim; ++jj) {
            rank += (rdlane_u64(kv, jj) > mykey) ? 1 : 0;
        }
    }
    if (own) s_sorted[rank] = k;    // keys unique -> rank is a bijection over 300 rois
    __syncthreads();
    if (wave != 0) return;

    // ================== wave 0 only from here ==================

    // ---- gather decoded boxes into sorted-order registers; area from same values ----
    float4 bx[5];
    float  area[5];
    unsigned keep = 0;
    #pragma unroll
    for (int s = 0; s < 5; ++s) {
        const int j   = s * 64 + lane;
        const int idx = (j < RR) ? s_sorted[j] : 0;
        bx[s]   = s_box[idx];
        area[s] = (bx[s].z - bx[s].x + 1.0f) * (bx[s].w - bx[s].y + 1.0f);
        keep |= ((j < nv) ? 1u : 0u) << s;
    }

    // ---- greedy scan; ctz skips suppressed boxes (proven R4/R5) ----
    #pragma unroll
    for (int w = 0; w < 5; ++w) {
        if (w * 64 < nv) {
            unsigned long long mask = __ballot((keep >> w) & 1u);
            while (mask) {
                const int tb = (int)__builtin_ctzll(mask);
                const float bix  = rdlane_f(bx[w].x, tb);
                const float biy  = rdlane_f(bx[w].y, tb);
                const float biz  = rdlane_f(bx[w].z, tb);
                const float biw  = rdlane_f(bx[w].w, tb);
                const float ar_i = rdlane_f(area[w], tb);
                #pragma unroll
                for (int s2 = w; s2 < 5; ++s2) {
                    if (s2 * 64 < nv) {             // uniform gate
                        float xx1 = fmaxf(bix, bx[s2].x);
                        float yy1 = fmaxf(biy, bx[s2].y);
                        float xx2 = fminf(biz, bx[s2].z);
                        float yy2 = fminf(biw, bx[s2].w);
                        float inter = fmaxf(xx2 - xx1 + 1.0f, 0.0f) * fmaxf(yy2 - yy1 + 1.0f, 0.0f);
                        float iou = inter / (ar_i + area[s2] - inter);
                        bool gtr = (s2 > w) || (lane > tb);     // j > i
                        bool sup = gtr && (iou > NMS_THR);
                        keep &= ~(((unsigned)sup) << s2);       // j >= nv bits already 0
                    }
                }
                mask = __ballot((keep >> w) & 1u) & ~((2ull << tb) - 1ull);
            }
        }
    }

    // ---- ballot prefix-popcount output compaction ----
    int total = 0;
    #pragma unroll
    for (int s = 0; s < 5; ++s) {
        const unsigned long long m = __ballot((keep >> s) & 1u);
        const bool mine = (keep >> s) & 1u;
        const int p = total + (int)__popcll(m & ((1ull << lane) - 1ull));
        if (mine && p < KK) {
            float* dst = wsBoxes + (((size_t)(b * NFG + ci)) * KK + p) * 4;
            *(float4*)dst = bx[s];
        }
        total += (int)__popcll(m);
    }
    if (lane == 0) wsCount[b * NFG + ci] = total;
}

__global__ __launch_bounds__(64)
void select_topk_kernel(const float* __restrict__ wsBoxes,
                        const int*   __restrict__ wsCount,
                        float* __restrict__ out,   // [B,KK,5] then [B] counts
                        int B)
{
    const int b = blockIdx.x;
    const int tid = threadIdx.x;

    __shared__ int s_pref[NFG + 1];
    __shared__ int s_n;

    if (tid == 0) {
        int acc = 0, full = 0;
        for (int q = 0; q < NFG; ++q) {
            s_pref[q] = acc;
            int cc = wsCount[b * NFG + q];
            acc += (cc < KK) ? cc : KK;
            full += cc;
        }
        s_pref[NFG] = acc;
        s_n = (full < KK) ? full : KK;
    }
    __syncthreads();

    const int n = s_n;
    if (tid < KK) {
        float* ob = out + (size_t)b * (KK * 5) + tid * 5;
        if (tid < n) {
            int cc = 0;
            for (int q = 1; q < NFG; ++q) if (s_pref[q] <= tid) cc = q;
            const int slot = tid - s_pref[cc];
            const float* bp = wsBoxes + (((size_t)(b * NFG + cc)) * KK + slot) * 4;
            ob[0] = bp[0];
            ob[1] = bp[1];
            ob[2] = bp[2];
            ob[3] = bp[3];
            ob[4] = (float)(cc + 1);
        } else {
            ob[0] = 0.0f; ob[1] = 0.0f; ob[2] = 0.0f; ob[3] = 0.0f; ob[4] = 0.0f;
        }
    }
    if (tid == 0) out[(size_t)B * KK * 5 + b] = (float)n;
}

extern "C" void kernel_launch(void* const* d_in, const int* in_sizes, int n_in,
                              void* d_out, int out_size, void* d_ws, size_t ws_size,
                              hipStream_t stream)
{
    const float* cls_prob  = (const float*)d_in[0];
    const float* rois      = (const float*)d_in[1];
    const float* bbox_pred = (const float*)d_in[2];
    const float* im_info   = (const float*)d_in[3];
    const float* thr       = (const float*)d_in[4];
    const int B = in_sizes[3] / 3;   // im_info is [B,3]

    float* wsBoxes = (float*)d_ws;                                         // B*NFG*KK*4 floats
    int*   wsCount = (int*)((char*)d_ws + (size_t)B * NFG * KK * 4 * sizeof(float));

    nms_per_class_kernel<<<B * NFG, THREADS, 0, stream>>>(
        cls_prob, rois, bbox_pred, im_info, thr, wsBoxes, wsCount);
    select_topk_kernel<<<B, 64, 0, stream>>>(
        wsBoxes, wsCount, (float*)d_out, B);
}